// Round 12
// baseline (156.772 us; speedup 1.0000x reference)
//
#include <hip/hip_runtime.h>
#include <math.h>

namespace {

constexpr int Bn = 64, Cn = 128, Tn = 512, Hn = 256;
constexpr int MR = 64;        // t-rows per block
constexpr int TB = Tn / MR;   // 8 -> grid 512 (2 blocks/CU)
constexpr float LN_EPS = 1e-5f;

constexpr int L2S = 294912;   // short offset of L2 unit region (18*16384)
constexpr int ZR = 66;        // stash row stride in shorts (33 dw -> conflict-free)

typedef __attribute__((ext_vector_type(8))) short short8;
typedef __attribute__((ext_vector_type(16))) float f32x16;

__device__ __forceinline__ unsigned short f2bf(float f) {
  unsigned int u = __builtin_bit_cast(unsigned int, f);
  u = (u + 0x7fffu + ((u >> 16) & 1u)) >> 16;
  return (unsigned short)u;
}
__device__ __forceinline__ float bf2f(unsigned short u) {
  unsigned int v = (unsigned int)u << 16;
  return __builtin_bit_cast(float, v);
}
__device__ __forceinline__ float siluf(float z) {
  return z * __builtin_amdgcn_rcpf(1.0f + __expf(-z));
}

// Closed-form uniform cubic B-spline on grid g[j]=0.4*(j-3)-1; 8 bases bf16.
__device__ __forceinline__ short8 spline_pack(float z) {
  const float p = z * 2.5f + 5.5f;
  const float fi = floorf(p);
  const int ib = (int)fi - 3;
  const float u = p - fi;
  const float u2 = u * u, u3 = u2 * u, tt = 1.0f - u;
  const float w0 = tt * tt * tt * (1.0f / 6.0f);
  const float w1 = (3.0f * u3 - 6.0f * u2 + 4.0f) * (1.0f / 6.0f);
  const float w2 = (-3.0f * u3 + 3.0f * u2 + 3.0f * u + 1.0f) * (1.0f / 6.0f);
  const float w3 = u3 * (1.0f / 6.0f);
  short8 r;
#pragma unroll
  for (int j = 0; j < 8; ++j) {
    const int d = j - ib;
    const float v =
        (d == 0) ? w0 : (d == 1) ? w1 : (d == 2) ? w2 : (d == 3) ? w3 : 0.0f;
    r[j] = (short)f2bf(v);
  }
  return r;
}

}  // namespace

#define BAR_LGKM()                                     \
  do {                                                 \
    asm volatile("s_waitcnt lgkmcnt(0)" ::: "memory"); \
    __builtin_amdgcn_s_barrier();                      \
    asm volatile("" ::: "memory");                     \
  } while (0)

// ---------------------------------------------------------------------------
// Prep: fragment-linear weight pack for k=64 units; LN partial sums; bf16
// transpose of ln_w/ln_b to [c][t].
// L1 units 0..15 spline (granule=c&7 of unit c>>3), 16..17 silu.
// L2 units 18..49 spline, 50..53 silu.  Frag addr: (g*N + n)*8 + j.
// ---------------------------------------------------------------------------
__global__ __launch_bounds__(256) void kan_prep(
    const float* __restrict__ U, const float* __restrict__ ln_w,
    const float* __restrict__ ln_b, const float* __restrict__ bw1,
    const float* __restrict__ sw1, const float* __restrict__ ss1,
    const float* __restrict__ bw2, const float* __restrict__ sw2,
    const float* __restrict__ ss2, unsigned short* __restrict__ Wp,
    unsigned short* __restrict__ lnwT, unsigned short* __restrict__ lnbT,
    float* __restrict__ stats) {
  __shared__ float red[2][4];
  const int blk = blockIdx.x;
  if (blk < 128) {  // ---- W1: idx = h*128 + c ----
    const int idx = blk * 256 + threadIdx.x;
    const int h = idx >> 7, c = idx & 127;
    const float sc = ss1[idx];
    const float* spw = sw1 + (size_t)idx * 8;
    short8 v;
#pragma unroll
    for (int j = 0; j < 8; ++j) v[j] = (short)f2bf(spw[j] * sc);
    *(short8*)(Wp + (size_t)(c >> 3) * 16384 + ((c & 7) * 256 + h) * 8) = v;
    Wp[(size_t)(16 + (c >> 6)) * 16384 + (((c >> 3) & 7) * 256 + h) * 8 +
       (c & 7)] = f2bf(bw1[idx]);
  } else if (blk < 256) {  // ---- W2: idx = c*256 + h ----
    const int idx = (blk - 128) * 256 + threadIdx.x;
    const int c = idx >> 8, h = idx & 255;
    const float sc = ss2[idx];
    const float* spw = sw2 + (size_t)idx * 8;
    short8 v;
#pragma unroll
    for (int j = 0; j < 8; ++j) v[j] = (short)f2bf(spw[j] * sc);
    *(short8*)(Wp + L2S + (size_t)(h >> 3) * 8192 + ((h & 7) * 128 + c) * 8) =
        v;
    Wp[L2S + (size_t)(32 + (h >> 6)) * 8192 + (((h >> 3) & 7) * 128 + c) * 8 +
       (h & 7)] = f2bf(bw2[idx]);
  } else if (blk < 512) {  // ---- LN stats partials ----
    const int sblk = blk - 256;
    const int b = sblk >> 2, q = sblk & 3;
    const float4* p =
        (const float4*)(U + (size_t)b * (Cn * Tn) + q * (Cn * Tn / 4));
    float s = 0.f, s2 = 0.f;
#pragma unroll 4
    for (int i = threadIdx.x; i < (Cn * Tn / 4) / 4; i += 256) {
      const float4 v4 = p[i];
      s += v4.x + v4.y + v4.z + v4.w;
      s2 += v4.x * v4.x + v4.y * v4.y + v4.z * v4.z + v4.w * v4.w;
    }
#pragma unroll
    for (int off = 32; off > 0; off >>= 1) {
      s += __shfl_down(s, off);
      s2 += __shfl_down(s2, off);
    }
    if ((threadIdx.x & 63) == 0) {
      red[0][threadIdx.x >> 6] = s;
      red[1][threadIdx.x >> 6] = s2;
    }
    __syncthreads();
    if (threadIdx.x == 0) {
      stats[b * 8 + q * 2 + 0] = red[0][0] + red[0][1] + red[0][2] + red[0][3];
      stats[b * 8 + q * 2 + 1] = red[1][0] + red[1][1] + red[1][2] + red[1][3];
    }
  } else {  // ---- ln_w/ln_b transpose to bf16 [c][t] ----
    const int bb = blk - 512;
    const float* src = (bb < 64) ? ln_w : ln_b;
    unsigned short* dst = (bb < 64) ? lnwT : lnbT;
    const int base = (bb & 63) * 1024;
#pragma unroll
    for (int e2 = 0; e2 < 4; ++e2) {
      const int i = base + (int)threadIdx.x + e2 * 256;
      dst[i] = f2bf(src[(i & 511) * Cn + (i >> 9)]);
    }
  }
}

// ---------------------------------------------------------------------------
// Fused LN -> KAN1 -> KAN2 -> residual.
// 512 blocks x 256 threads (4 waves: wave w = n-group; m = 64 rows each).
// B: global -> VGPR, half-unit software pipeline (no LDS pipe use).
// A: act LDS, granule-major [g][row] (conflict-free), one spline/thread.
// z1/h1 stashes [feat][row] stride 66 (conflict-free). 54 units, 54 barriers
// (lgkm-only: B-loads stay in flight across barriers).
// ---------------------------------------------------------------------------
__global__ __launch_bounds__(256, 2) void kan_fused(
    const float* __restrict__ U, const unsigned short* __restrict__ lnwT,
    const unsigned short* __restrict__ lnbT,
    const unsigned short* __restrict__ Wp, const float* __restrict__ stats,
    float* __restrict__ out) {
  __shared__ __align__(16) unsigned short s_z1[Cn * ZR];   // 16,896 B
  __shared__ __align__(16) unsigned short s_h1[Hn * ZR];   // 33,792 B
  __shared__ __align__(16) unsigned short s_act[2][4096];  // 16,384 B

  const int tid = threadIdx.x;
  const int b = blockIdx.x >> 3;
  const int t0 = (blockIdx.x & 7) * MR;

  const float* sp = stats + b * 8;
  const float ssum = sp[0] + sp[2] + sp[4] + sp[6];
  const float ssq = sp[1] + sp[3] + sp[5] + sp[7];
  const float inv_n = 1.0f / (float)(Cn * Tn);
  const float mean = ssum * inv_n;
  const float rstd = rsqrtf(ssq * inv_n - mean * mean + LN_EPS);

  const int w = tid >> 6, l = tid & 63;   // wave = n-group
  const int ln31 = l & 31, hl = l >> 5;
  const int arow = tid & 63, ag = tid >> 6;  // act producer mapping

  // ---- B loads: fragment-linear, coalesced, straight to VGPR ----
  auto ldL1 = [&](int u, int hf, short8(&d)[4]) {
    const unsigned short* bp = Wp + (size_t)u * 16384;
#pragma unroll
    for (int gl = 0; gl < 2; ++gl)
#pragma unroll
      for (int f = 0; f < 2; ++f)
        d[gl * 2 + f] = *(const short8*)(bp + ((2 * (hf * 2 + gl) + hl) * 256 +
                                               w * 64 + f * 32 + ln31) *
                                                  8);
  };
  auto ldL2 = [&](int u, int hf, short8(&d)[2]) {
    const unsigned short* bp = Wp + (size_t)L2S + (size_t)(u - 18) * 8192;
#pragma unroll
    for (int gl = 0; gl < 2; ++gl)
      d[gl] = *(const short8*)(bp + ((2 * (hf * 2 + gl) + hl) * 128 + w * 32 +
                                     ln31) *
                                        8);
  };

  f32x16 acc1[2][2] = {};
  f32x16 acc2[2] = {};

  auto mm1 = [&](const unsigned short* ab, int hf, const short8(&d)[4]) {
#pragma unroll
    for (int gl = 0; gl < 2; ++gl) {
      const int g2 = (hf * 2 + gl) * 2 + hl;  // this lane's granule
#pragma unroll
      for (int mf = 0; mf < 2; ++mf) {
        const short8 a = *(const short8*)(ab + (g2 * 64 + mf * 32 + ln31) * 8);
#pragma unroll
        for (int f = 0; f < 2; ++f)
          acc1[mf][f] = __builtin_amdgcn_mfma_f32_32x32x16_bf16(
              a, d[gl * 2 + f], acc1[mf][f], 0, 0, 0);
      }
    }
  };
  auto mm2 = [&](const unsigned short* ab, int hf, const short8(&d)[2]) {
#pragma unroll
    for (int gl = 0; gl < 2; ++gl) {
      const int g2 = (hf * 2 + gl) * 2 + hl;
#pragma unroll
      for (int mf = 0; mf < 2; ++mf) {
        const short8 a = *(const short8*)(ab + (g2 * 64 + mf * 32 + ln31) * 8);
        acc2[mf] = __builtin_amdgcn_mfma_f32_32x32x16_bf16(a, d[gl], acc2[mf],
                                                           0, 0, 0);
      }
    }
  };

  // ---- act producer: (8 granules x 64 rows) = 2 entries per thread ----
  auto actp = [&](int u, unsigned short* abuf) {
#pragma unroll
    for (int p = 0; p < 2; ++p) {
      const int g = ag + p * 4;
      unsigned short* dst = abuf + (g * 64 + arow) * 8;
      if (u < 16) {
        *(short8*)dst = spline_pack(bf2f(s_z1[(u * 8 + g) * ZR + arow]));
      } else if (u < 18) {
        const int cb = (u - 16) * 64 + g * 8;
        short8 v;
#pragma unroll
        for (int j = 0; j < 8; ++j)
          v[j] = (short)f2bf(siluf(bf2f(s_z1[(cb + j) * ZR + arow])));
        *(short8*)dst = v;
      } else if (u < 50) {
        *(short8*)dst = spline_pack(bf2f(s_h1[((u - 18) * 8 + g) * ZR + arow]));
      } else {
        const int hb = (u - 50) * 64 + g * 8;
        short8 v;
#pragma unroll
        for (int j = 0; j < 8; ++j)
          v[j] = (short)f2bf(siluf(bf2f(s_h1[(hb + j) * ZR + arow])));
        *(short8*)dst = v;
      }
    }
  };

  // =========================== prologue ===========================
  short8 P[4], Q[4];
  short8 P2[2], Q2[2];
  ldL1(0, 0, P);
  ldL1(0, 1, Q);
  // z1: LN of the 128c x 64row tile -> stash (coalesced float4 U reads)
#pragma unroll
  for (int i = 0; i < 8; ++i) {
    const int slot = tid + i * 256;  // 2048 slots = 128c x 16 row-quads
    const int c = slot >> 4, rq = slot & 15;
    const float4 u4 = *(const float4*)&U[((size_t)b * Cn + c) * Tn + t0 + rq * 4];
    const unsigned short* lw = &lnwT[c * Tn + t0 + rq * 4];
    const unsigned short* lb = &lnbT[c * Tn + t0 + rq * 4];
    const float zz[4] = {u4.x, u4.y, u4.z, u4.w};
#pragma unroll
    for (int k2 = 0; k2 < 4; ++k2)
      s_z1[c * ZR + rq * 4 + k2] =
          f2bf((zz[k2] - mean) * rstd * bf2f(lw[k2]) + bf2f(lb[k2]));
  }
  BAR_LGKM();
  actp(0, &s_act[0][0]);
  BAR_LGKM();

  // ==================== Layer 1: units 0..17 ====================
  for (int u = 0; u < 17; ++u) {
    const unsigned short* ab = &s_act[u & 1][0];
    __builtin_amdgcn_s_setprio(1);
    mm1(ab, 0, P);
    __builtin_amdgcn_s_setprio(0);
    ldL1(u + 1, 0, P);
    __builtin_amdgcn_s_setprio(1);
    mm1(ab, 1, Q);
    __builtin_amdgcn_s_setprio(0);
    ldL1(u + 1, 1, Q);
    actp(u + 1, &s_act[(u + 1) & 1][0]);
    BAR_LGKM();
  }
  {  // u = 17: last L1 unit; prefetch L2 unit 18; h1 epilogue; act(18)
    const unsigned short* ab = &s_act[1][0];
    mm1(ab, 0, P);
    ldL2(18, 0, P2);
    mm1(ab, 1, Q);
    ldL2(18, 1, Q2);
    // h1 -> stash [h][row] (conflict-free: bank = h mod 32 = ln31)
#pragma unroll
    for (int mf = 0; mf < 2; ++mf)
#pragma unroll
      for (int f = 0; f < 2; ++f)
#pragma unroll
        for (int r = 0; r < 16; ++r) {
          const int row = mf * 32 + 4 * hl + (r & 3) + 8 * (r >> 2);
          const int h = w * 64 + f * 32 + ln31;
          s_h1[h * ZR + row] = f2bf(acc1[mf][f][r]);
        }
    BAR_LGKM();
    actp(18, &s_act[0][0]);
    BAR_LGKM();
  }

  // ==================== Layer 2: units 18..53 ====================
  for (int u = 18; u < 54; ++u) {
    const unsigned short* ab = &s_act[u & 1][0];
    __builtin_amdgcn_s_setprio(1);
    mm2(ab, 0, P2);
    __builtin_amdgcn_s_setprio(0);
    if (u < 53) ldL2(u + 1, 0, P2);
    __builtin_amdgcn_s_setprio(1);
    mm2(ab, 1, Q2);
    __builtin_amdgcn_s_setprio(0);
    if (u < 53) ldL2(u + 1, 1, Q2);
    if (u < 53) actp(u + 1, &s_act[(u + 1) & 1][0]);
    BAR_LGKM();
  }

  // ============== epilogue: LDS bounce -> coalesced residual ==============
  float* ob = (float*)&s_h1[0];  // 128c x 64row f32 = 32 KB (<= h1 region)
#pragma unroll
  for (int mf = 0; mf < 2; ++mf)
#pragma unroll
    for (int r = 0; r < 16; ++r) {
      const int c = w * 32 + ln31;
      const int row = mf * 32 + 4 * hl + (r & 3) + 8 * (r >> 2);
      ob[c * 64 + (row ^ ((c & 15) << 2))] = acc2[mf][r];
    }
  BAR_LGKM();
#pragma unroll
  for (int i = 0; i < 8; ++i) {
    const int slot = tid + i * 256;  // 2048 float4 slots
    const int c = slot >> 4, rq = slot & 15;
    const float4 v = *(const float4*)&ob[c * 64 + ((rq * 4) ^ ((c & 15) << 2))];
    const size_t ga = ((size_t)b * Cn + c) * Tn + t0 + rq * 4;
    const float4 u4 = *(const float4*)&U[ga];
    float4 o;
    o.x = u4.x + v.x;
    o.y = u4.y + v.y;
    o.z = u4.z + v.z;
    o.w = u4.w + v.w;
    *(float4*)&out[ga] = o;
  }
}

extern "C" void kernel_launch(void* const* d_in, const int* in_sizes, int n_in,
                              void* d_out, int out_size, void* d_ws,
                              size_t ws_size, hipStream_t stream) {
  const float* U = (const float*)d_in[0];
  const float* ln_w = (const float*)d_in[1];
  const float* ln_b = (const float*)d_in[2];
  const float* bw1 = (const float*)d_in[3];
  const float* sw1 = (const float*)d_in[4];
  const float* ss1 = (const float*)d_in[5];
  const float* bw2 = (const float*)d_in[6];
  const float* sw2 = (const float*)d_in[7];
  const float* ss2 = (const float*)d_in[8];
  float* out = (float*)d_out;

  char* ws = (char*)d_ws;
  float* stats = (float*)ws;                            // 4 KB
  unsigned short* lnwT = (unsigned short*)(ws + 4096);  // 128 KB
  unsigned short* lnbT = lnwT + Cn * Tn;                // 128 KB
  unsigned short* Wp = lnbT + Cn * Tn;                  // 1,179,648 B packed W

  kan_prep<<<640, 256, 0, stream>>>(U, ln_w, ln_b, bw1, sw1, ss1, bw2, sw2,
                                    ss2, Wp, lnwT, lnbT, stats);
  kan_fused<<<Bn * TB, 256, 0, stream>>>(U, lnwT, lnbT, Wp, stats, out);
}